// Round 4
// baseline (1951.747 us; speedup 1.0000x reference)
//
#include <hip/hip_runtime.h>
#include <hip/hip_bf16.h>
#include <cstdint>
#include <cstddef>

#define F_DIMC 256
#define FHC    1024
#define IMGH   160
#define IMGW   160
#define NTOK   25600
#define NLAY   4

using bf16 = __hip_bfloat16;
typedef __attribute__((ext_vector_type(8))) short bf16x8;
typedef __attribute__((ext_vector_type(4))) float f32x4;

#define MFMA16(a, b, c) __builtin_amdgcn_mfma_f32_16x16x32_bf16((a), (b), (c), 0, 0, 0)

// ---------------- weight converts (merged) ----------------
struct Cvt6 { const float* s[6]; bf16* d[6]; };
__global__ void cvt6_k(Cvt6 a, int n) {
    int z = blockIdx.y;
    int i = blockIdx.x * 256 + threadIdx.x;
    if (i < n) a.d[z][i] = __float2bfloat16(a.s[z][i]);
}
struct Cvt2 { const float* s[2]; bf16* d[2]; };
__global__ void cvt2_k(Cvt2 a, int n) {
    int z = blockIdx.y;
    int i = blockIdx.x * 256 + threadIdx.x;
    if (i < n) a.d[z][i] = __float2bfloat16(a.s[z][i]);
}

// spa_dw_w (L,F,49) -> dwT (L,49,F) fp32
__global__ void dw_transpose_k(const float* __restrict__ src, float* __restrict__ dst, int n) {
    int i = blockIdx.x * 256 + threadIdx.x;
    if (i < n) {
        int f = i & (F_DIMC - 1);
        int lt = i >> 8;
        int t = lt % 49;
        int l = lt / 49;
        dst[i] = src[((size_t)l * F_DIMC + f) * 49 + t];
    }
}

// ---------------- stem: branchless, strip-parallel ---------------------------
__global__ __launch_bounds__(256)
void stem2_k(const float* __restrict__ x, const float* __restrict__ w1,
             const float* __restrict__ b1, const float* __restrict__ w2,
             const float* __restrict__ b2, float* __restrict__ d)
{
    __shared__ float wts[49][64];
    __shared__ float w1s[64], b1s[64], b2s[64];
    __shared__ float2 xp[7][22];
    const int tid = threadIdx.x;
    const int f0 = blockIdx.y * 64;
    const int y = blockIdx.x / 10;
    const int x0 = (blockIdx.x % 10) * 16;

    for (int idx = tid; idx < 49 * 64; idx += 256) {
        int t = idx >> 6, fl = idx & 63;
        wts[t][fl] = w2[(f0 + fl) * 49 + t];
    }
    if (tid < 64) {
        w1s[tid] = w1[f0 + tid];
        b1s[tid] = b1[f0 + tid];
        b2s[tid] = b2[f0 + tid];
    }
    for (int p = tid; p < 7 * 22; p += 256) {
        int py = p / 22, px = p % 22;
        int gy = y + py - 3, gx = x0 + px - 3;
        bool ok = (unsigned)gy < IMGH && (unsigned)gx < IMGW;
        xp[py][px] = ok ? make_float2(x[gy * IMGW + gx], 1.f) : make_float2(0.f, 0.f);
    }
    __syncthreads();

    const int fl = tid & 63;
    const int xbase = (tid >> 6) * 4;
    float acc[4] = {0.f, 0.f, 0.f, 0.f}, accw[4] = {0.f, 0.f, 0.f, 0.f};
    #pragma unroll
    for (int ky = 0; ky < 7; ++ky) {
        float2 row[10];
        #pragma unroll
        for (int q = 0; q < 10; ++q) row[q] = xp[ky][xbase + q];
        #pragma unroll
        for (int kx = 0; kx < 7; ++kx) {
            float w = wts[ky * 7 + kx][fl];
            #pragma unroll
            for (int j = 0; j < 4; ++j) {
                acc[j]  = fmaf(row[j + kx].x, w, acc[j]);
                accw[j] = fmaf(row[j + kx].y, w, accw[j]);
            }
        }
    }
    const float w1f = w1s[fl], b1f = b1s[fl], b2f = b2s[fl];
    #pragma unroll
    for (int j = 0; j < 4; ++j) {
        float u = fmaf(w1f, acc[j], fmaf(b1f, accw[j], b2f));
        int pix = y * IMGW + x0 + xbase + j;
        d[(size_t)pix * F_DIMC + f0 + fl] = u / (1.f + __expf(-4.f * u));
    }
}

// ---------------- wave-level LayerNorm over F=256 ----------------------------
__device__ __forceinline__ void wave_ln(float* x, const float* __restrict__ w,
                                        const float* __restrict__ b, int lane)
{
    float s = x[0] + x[1] + x[2] + x[3];
    #pragma unroll
    for (int m = 1; m < 64; m <<= 1) s += __shfl_xor(s, m, 64);
    float mu = s * 0.00390625f;
    float t0 = x[0] - mu, t1 = x[1] - mu, t2 = x[2] - mu, t3 = x[3] - mu;
    float v = t0 * t0 + t1 * t1 + t2 * t2 + t3 * t3;
    #pragma unroll
    for (int m = 1; m < 64; m <<= 1) v += __shfl_xor(v, m, 64);
    float inv = rsqrtf(v * 0.00390625f + 1e-5f);
    f32x4 wv = *(const f32x4*)(w + lane * 4);
    f32x4 bv = *(const f32x4*)(b + lane * 4);
    x[0] = t0 * inv * wv[0] + bv[0];
    x[1] = t1 * inv * wv[1] + bv[1];
    x[2] = t2 * inv * wv[2] + bv[2];
    x[3] = t3 * inv * wv[3] + bv[3];
}

union Pack4 { bf16 h[4]; uint2 u; };

template<bool LN0>
__global__ __launch_bounds__(256)
void lnmix_sa_k(float* __restrict__ d, const float* __restrict__ sp,
                const float* __restrict__ ln0w, const float* __restrict__ ln0b,
                const float* __restrict__ lnw, const float* __restrict__ lnb,
                const float* __restrict__ tmk, const float* __restrict__ tmv,
                const float* __restrict__ tmr,
                bf16* __restrict__ xk, bf16* __restrict__ xv, bf16* __restrict__ xr)
{
    const int lane = threadIdx.x & 63;
    const int n = blockIdx.x * 4 + (threadIdx.x >> 6);
    const int base = n * F_DIMC + lane * 4;
    f32x4 dv = *(const f32x4*)(d + base);
    float xo[4] = {dv[0], dv[1], dv[2], dv[3]};
    if (LN0) {
        wave_ln(xo, ln0w, ln0b, lane);
        f32x4 o = {xo[0], xo[1], xo[2], xo[3]};
        *(f32x4*)(d + base) = o;
    }
    float xs[4] = {xo[0], xo[1], xo[2], xo[3]};
    wave_ln(xs, lnw, lnb, lane);
    f32x4 spv = *(const f32x4*)(sp + base);
    f32x4 k4 = *(const f32x4*)(tmk + lane * 4);
    f32x4 v4 = *(const f32x4*)(tmv + lane * 4);
    f32x4 r4 = *(const f32x4*)(tmr + lane * 4);
    Pack4 pk, pv, pr;
    #pragma unroll
    for (int j = 0; j < 4; ++j) {
        pk.h[j] = __float2bfloat16(xs[j] * k4[j] + spv[j] * (1.f - k4[j]));
        pv.h[j] = __float2bfloat16(xs[j] * v4[j] + spv[j] * (1.f - v4[j]));
        pr.h[j] = __float2bfloat16(xs[j] * r4[j] + spv[j] * (1.f - r4[j]));
    }
    *(uint2*)(xk + base) = pk.u;
    *(uint2*)(xv + base) = pv.u;
    *(uint2*)(xr + base) = pr.u;
}

__global__ __launch_bounds__(256)
void lnmix_ff_k(const float* __restrict__ d, const float* __restrict__ sp,
                const float* __restrict__ lnw, const float* __restrict__ lnb,
                const float* __restrict__ tmk, const float* __restrict__ tmr,
                bf16* __restrict__ xk, bf16* __restrict__ xr)
{
    const int lane = threadIdx.x & 63;
    const int n = blockIdx.x * 4 + (threadIdx.x >> 6);
    const int base = n * F_DIMC + lane * 4;
    f32x4 dv = *(const f32x4*)(d + base);
    float xs[4] = {dv[0], dv[1], dv[2], dv[3]};
    wave_ln(xs, lnw, lnb, lane);
    f32x4 spv = *(const f32x4*)(sp + base);
    f32x4 k4 = *(const f32x4*)(tmk + lane * 4);
    f32x4 r4 = *(const f32x4*)(tmr + lane * 4);
    Pack4 pk, pr;
    #pragma unroll
    for (int j = 0; j < 4; ++j) {
        pk.h[j] = __float2bfloat16(xs[j] * k4[j] + spv[j] * (1.f - k4[j]));
        pr.h[j] = __float2bfloat16(xs[j] * r4[j] + spv[j] * (1.f - r4[j]));
    }
    *(uint2*)(xk + base) = pk.u;
    *(uint2*)(xr + base) = pr.u;
}

// ---------------- swizzled staging + fragment loads --------------------------
// LDS rows hold a swizzled permutation: 16B chunk c16 of row holds global chunk
// c16 ^ (row&15). ds_read applies the same XOR => conflict-free b128 reads.

// 256-col rows (512B), 64 rows => 2048 chunks
__device__ __forceinline__ void stage_swz32(const bf16* __restrict__ g,
                                            bf16* lds, int tid)
{
    #pragma unroll
    for (int s = 0; s < 8; ++s) {
        int chunk = s * 256 + tid;
        int row = chunk >> 5, c16 = chunk & 31;
        int gc = c16 ^ (row & 15);
        __builtin_amdgcn_global_load_lds(
            (const __attribute__((address_space(1))) void*)(g + (size_t)row * 256 + gc * 8),
            (__attribute__((address_space(3))) void*)(lds + chunk * 8), 16, 0, 0);
    }
}

// 128-col rows (256B), 128 rows => 2048 chunks; lda in elems
__device__ __forceinline__ void stage_swz16(const bf16* __restrict__ g, int lda,
                                            bf16* lds, int tid)
{
    #pragma unroll
    for (int s = 0; s < 8; ++s) {
        int chunk = s * 256 + tid;
        int row = chunk >> 4, c16 = chunk & 15;
        int gc = c16 ^ (row & 15);
        __builtin_amdgcn_global_load_lds(
            (const __attribute__((address_space(1))) void*)(g + (size_t)row * lda + gc * 8),
            (__attribute__((address_space(3))) void*)(lds + chunk * 8), 16, 0, 0);
    }
}

template<int RB>
__device__ __forceinline__ bf16x8 frag_ld(const bf16* lds, int row, int cb)
{
    return *(const bf16x8*)((const char*)lds + row * RB + (cb ^ ((row & 15) << 4)));
}

// ---------------- sawkv: 3 GEMMs (k,v,r) + WKV epilogue ----------------------
// 64x64 tile, single-shot K=256. grid (400, 4).
__device__ __forceinline__ void pass64(const bf16* __restrict__ Ag, const bf16* __restrict__ Bg,
                                       bf16* As, bf16* Bs, int tid, int wr, int wc,
                                       int lr, int hi, f32x4 (&acc)[2][2])
{
    stage_swz32(Ag, As, tid);
    stage_swz32(Bg, Bs, tid);
    __syncthreads();
    #pragma unroll
    for (int ks = 0; ks < 8; ++ks) {
        int cb = ks * 64 + hi * 16;
        bf16x8 a0 = frag_ld<512>(As, wr * 32 + lr, cb);
        bf16x8 a1 = frag_ld<512>(As, wr * 32 + 16 + lr, cb);
        bf16x8 b0 = frag_ld<512>(Bs, wc * 32 + lr, cb);
        bf16x8 b1 = frag_ld<512>(Bs, wc * 32 + 16 + lr, cb);
        acc[0][0] = MFMA16(a0, b0, acc[0][0]);
        acc[0][1] = MFMA16(a0, b1, acc[0][1]);
        acc[1][0] = MFMA16(a1, b0, acc[1][0]);
        acc[1][1] = MFMA16(a1, b1, acc[1][1]);
    }
    __syncthreads();
}

__global__ __launch_bounds__(256, 2)
void sawkv_k(const bf16* __restrict__ xk, const bf16* __restrict__ xv,
             const bf16* __restrict__ xr,
             const bf16* __restrict__ kw, const bf16* __restrict__ vw,
             const bf16* __restrict__ rw,
             const float* __restrict__ aa, const float* __restrict__ bb,
             const float* __restrict__ pp, const float* __restrict__ tf,
             bf16* __restrict__ ab)
{
    __shared__ __align__(16) bf16 As[64 * 256];
    __shared__ __align__(16) bf16 Bs[64 * 256];
    const int tid = threadIdx.x, lane = tid & 63, wave = tid >> 6;
    const int wr = wave >> 1, wc = wave & 1;
    const int lr = lane & 15, hi = lane >> 4;
    const int m0 = blockIdx.x * 64, n0 = blockIdx.y * 64;

    f32x4 ak[2][2], av[2][2], ar[2][2];
    #pragma unroll
    for (int m = 0; m < 2; ++m)
        #pragma unroll
        for (int n = 0; n < 2; ++n) {
            ak[m][n] = (f32x4){0.f, 0.f, 0.f, 0.f};
            av[m][n] = (f32x4){0.f, 0.f, 0.f, 0.f};
            ar[m][n] = (f32x4){0.f, 0.f, 0.f, 0.f};
        }

    pass64(xk + (size_t)m0 * 256, kw + (size_t)n0 * 256, As, Bs, tid, wr, wc, lr, hi, ak);
    pass64(xv + (size_t)m0 * 256, vw + (size_t)n0 * 256, As, Bs, tid, wr, wc, lr, hi, av);
    pass64(xr + (size_t)m0 * 256, rw + (size_t)n0 * 256, As, Bs, tid, wr, wc, lr, hi, ar);

    const int lr0 = hi * 4;
    #pragma unroll
    for (int mf = 0; mf < 2; ++mf)
        #pragma unroll
        for (int nf = 0; nf < 2; ++nf) {
            int col = n0 + wc * 32 + nf * 16 + lr;
            float tfc = tf[col];
            #pragma unroll
            for (int j = 0; j < 4; ++j) {
                int row = m0 + wr * 32 + mf * 16 + lr0 + j;
                size_t idx = (size_t)row * F_DIMC + col;
                float kk = ak[mf][nf][j], vv = av[mf][nf][j], rr = ar[mf][nf][j];
                float P = pp[idx];
                float ww = tfc + kk;
                float p = fmaxf(P, ww);
                float e1 = __expf(P - p), e2 = __expf(ww - p);
                float wkv = (e1 * aa[idx] + e2 * vv) / (e1 * bb[idx] + e2);
                ab[idx] = __float2bfloat16(wkv / (1.f + __expf(-rr)));
            }
        }
}

// ---------------- gemm128: 128x128 tile, BK=128, swizzled --------------------
// EPI: 2 = relu^2 -> bf16, 3 = Cf += v, 5 = Cf += v + bias[col]
template<int EPI>
__global__ __launch_bounds__(256, 2)
void gemm128_k(const bf16* __restrict__ A, const bf16* __restrict__ Bw,
               int lda, int ldb, int K, int Nout,
               float* __restrict__ Cf, bf16* __restrict__ Cb,
               const float* __restrict__ bias)
{
    __shared__ __align__(16) bf16 As[128 * 128];
    __shared__ __align__(16) bf16 Bs[128 * 128];
    const int tid = threadIdx.x, lane = tid & 63, wave = tid >> 6;
    const int wr = wave >> 1, wc = wave & 1;
    const int lr = lane & 15, hi = lane >> 4;
    const int m0 = blockIdx.x * 128, n0 = blockIdx.y * 128;

    f32x4 acc[4][4];
    #pragma unroll
    for (int m = 0; m < 4; ++m)
        #pragma unroll
        for (int n = 0; n < 4; ++n) acc[m][n] = (f32x4){0.f, 0.f, 0.f, 0.f};

    for (int kt = 0; kt < K; kt += 128) {
        stage_swz16(A + (size_t)m0 * lda + kt, lda, As, tid);
        stage_swz16(Bw + (size_t)n0 * ldb + kt, ldb, Bs, tid);
        __syncthreads();
        #pragma unroll
        for (int ks = 0; ks < 4; ++ks) {
            int cb = ks * 64 + hi * 16;
            bf16x8 a[4], b[4];
            #pragma unroll
            for (int mf = 0; mf < 4; ++mf) a[mf] = frag_ld<256>(As, wr * 64 + mf * 16 + lr, cb);
            #pragma unroll
            for (int nf = 0; nf < 4; ++nf) b[nf] = frag_ld<256>(Bs, wc * 64 + nf * 16 + lr, cb);
            #pragma unroll
            for (int mf = 0; mf < 4; ++mf)
                #pragma unroll
                for (int nf = 0; nf < 4; ++nf)
                    acc[mf][nf] = MFMA16(a[mf], b[nf], acc[mf][nf]);
        }
        __syncthreads();
    }

    const int lr0 = hi * 4;
    #pragma unroll
    for (int mf = 0; mf < 4; ++mf)
        #pragma unroll
        for (int nf = 0; nf < 4; ++nf) {
            int col = n0 + wc * 64 + nf * 16 + lr;
            #pragma unroll
            for (int j = 0; j < 4; ++j) {
                int row = m0 + wr * 64 + mf * 16 + lr0 + j;
                size_t cidx = (size_t)row * Nout + col;
                float v = acc[mf][nf][j];
                if constexpr (EPI == 2) { float t = fmaxf(v, 0.f); Cb[cidx] = __float2bfloat16(t * t); }
                else if constexpr (EPI == 3) Cf[cidx] += v;
                else if constexpr (EPI == 5) Cf[cidx] += v + bias[col];
            }
        }
}

// ---------------- fvw GEMM (K=1024) with fused rr = sigmoid(xr@rw^T) ---------
__global__ __launch_bounds__(256, 2)
void fvwrr_k(const bf16* __restrict__ kkb, const bf16* __restrict__ fvw,
             const bf16* __restrict__ xr, const bf16* __restrict__ rw,
             float* __restrict__ d)
{
    __shared__ __align__(16) bf16 As[128 * 128];
    __shared__ __align__(16) bf16 Bs[128 * 128];
    const int tid = threadIdx.x, lane = tid & 63, wave = tid >> 6;
    const int wr = wave >> 1, wc = wave & 1;
    const int lr = lane & 15, hi = lane >> 4;
    const int m0 = blockIdx.x * 128, n0 = blockIdx.y * 128;

    f32x4 arr[4][4], am[4][4];
    #pragma unroll
    for (int m = 0; m < 4; ++m)
        #pragma unroll
        for (int n = 0; n < 4; ++n) {
            arr[m][n] = (f32x4){0.f, 0.f, 0.f, 0.f};
            am[m][n]  = (f32x4){0.f, 0.f, 0.f, 0.f};
        }

    // rr phase: xr (lda 256) @ rw (ldb 256), K=256
    for (int kt = 0; kt < 256; kt += 128) {
        stage_swz16(xr + (size_t)m0 * 256 + kt, 256, As, tid);
        stage_swz16(rw + (size_t)n0 * 256 + kt, 256, Bs, tid);
        __syncthreads();
        #pragma unroll
        for (int ks = 0; ks < 4; ++ks) {
            int cb = ks * 64 + hi * 16;
            bf16x8 a[4], b[4];
            #pragma unroll
            for (int mf = 0; mf < 4; ++mf) a[mf] = frag_ld<256>(As, wr * 64 + mf * 16 + lr, cb);
            #pragma unroll
            for (int nf = 0; nf < 4; ++nf) b[nf] = frag_ld<256>(Bs, wc * 64 + nf * 16 + lr, cb);
            #pragma unroll
            for (int mf = 0; mf < 4; ++mf)
                #pragma unroll
                for (int nf = 0; nf < 4; ++nf)
                    arr[mf][nf] = MFMA16(a[mf], b[nf], arr[mf][nf]);
        }
        __syncthreads();
    }
    // main phase: kkb (lda 1024) @ fvw (ldb 1024), K=1024
    for (int kt = 0; kt < 1024; kt += 128) {
        stage_swz16(kkb + (size_t)m0 * 1024 + kt, 1024, As, tid);
        stage_swz16(fvw + (size_t)n0 * 1024 + kt, 1024, Bs, tid);
        __syncthreads();
        #pragma unroll
        for (int ks = 0; ks < 4; ++ks) {
            int cb = ks * 64 + hi * 16;
            bf16x8 a[4], b[4];
            #pragma unroll
            for (int mf = 0; mf < 4; ++mf) a[mf] = frag_ld<256>(As, wr * 64 + mf * 16 + lr, cb);
            #pragma unroll
            for (int nf = 0; nf < 4; ++nf) b[nf] = frag_ld<256>(Bs, wc * 64 + nf * 16 + lr, cb);
            #pragma unroll
            for (int mf = 0; mf < 4; ++mf)
                #pragma unroll
                for (int nf = 0; nf < 4; ++nf)
                    am[mf][nf] = MFMA16(a[mf], b[nf], am[mf][nf]);
        }
        __syncthreads();
    }

    const int lr0 = hi * 4;
    #pragma unroll
    for (int mf = 0; mf < 4; ++mf)
        #pragma unroll
        for (int nf = 0; nf < 4; ++nf) {
            int col = n0 + wc * 64 + nf * 16 + lr;
            #pragma unroll
            for (int j = 0; j < 4; ++j) {
                int row = m0 + wr * 64 + mf * 16 + lr0 + j;
                size_t cidx = (size_t)row * F_DIMC + col;
                float rr = 1.f / (1.f + __expf(-arr[mf][nf][j]));
                d[cidx] += rr * am[mf][nf][j];
            }
        }
}

// ---------------- depthwise 7x7 conv v2: 8x8 tile, register row reuse --------
__global__ __launch_bounds__(256)
void dwconv2_k(const float* __restrict__ d, const float* __restrict__ wT,
               const float* __restrict__ bias, bf16* __restrict__ out)
{
    __shared__ float patch[196][64];   // 14x14 halo x 64 features
    __shared__ float wt[49][64];
    const int lane = threadIdx.x;      // 0..63 feature
    const int ty = threadIdx.y;        // 0..3
    const int f0 = blockIdx.z * 64;
    const int w0 = blockIdx.x * 8, h0 = blockIdx.y * 8;

    for (int t = ty; t < 49; t += 4) wt[t][lane] = wT[t * F_DIMC + f0 + lane];
    for (int p = ty; p < 196; p += 4) {
        int py = p / 14, px = p % 14;
        int gy = h0 + py - 3, gx = w0 + px - 3;
        float v = 0.f;
        if ((unsigned)gy < IMGH && (unsigned)gx < IMGW)
            v = d[(size_t)(gy * IMGW + gx) * F_DIMC + f0 + lane];
        patch[p][lane] = v;
    }
    __syncthreads();

    const float b = bias[f0 + lane];
    #pragma unroll
    for (int rr = 0; rr < 2; ++rr) {
        int ry = ty * 2 + rr;
        float acc8[8];
        #pragma unroll
        for (int px = 0; px < 8; ++px) acc8[px] = b;
        #pragma unroll
        for (int ky = 0; ky < 7; ++ky) {
            float rowv[14];
            #pragma unroll
            for (int c = 0; c < 14; ++c) rowv[c] = patch[(ry + ky) * 14 + c][lane];
            #pragma unroll
            for (int kx = 0; kx < 7; ++kx) {
                float w = wt[ky * 7 + kx][lane];
                #pragma unroll
                for (int px = 0; px < 8; ++px)
                    acc8[px] = fmaf(rowv[px + kx], w, acc8[px]);
            }
        }
        #pragma unroll
        for (int px = 0; px < 8; ++px)
            out[(size_t)((h0 + ry) * IMGW + (w0 + px)) * F_DIMC + f0 + lane] = __float2bfloat16(acc8[px]);
    }
}

// ---------------- final (N,F) -> (F,H,W) transpose ---------------------------
__global__ __launch_bounds__(256)
void transpose_out_k(const float* __restrict__ d, float* __restrict__ out)
{
    __shared__ float tile[32][33];
    const int n0 = blockIdx.x * 32, f0 = blockIdx.y * 32;
    const int tx = threadIdx.x, ty = threadIdx.y;
    for (int r = ty; r < 32; r += 8) tile[r][tx] = d[(size_t)(n0 + r) * F_DIMC + f0 + tx];
    __syncthreads();
    for (int r = ty; r < 32; r += 8) out[(size_t)(f0 + r) * NTOK + n0 + tx] = tile[tx][r];
}

// =============================================================================
extern "C" void kernel_launch(void* const* d_in, const int* in_sizes, int n_in,
                              void* d_out, int out_size, void* d_ws, size_t ws_size,
                              hipStream_t stream)
{
    if (n_in < 30) return;
    const float* x        = (const float*)d_in[0];
    const float* cin_w1   = (const float*)d_in[1];
    const float* cin_b1   = (const float*)d_in[2];
    const float* cin_w2   = (const float*)d_in[3];
    const float* cin_b2   = (const float*)d_in[4];
    const float* ln0_w    = (const float*)d_in[5];
    const float* ln0_b    = (const float*)d_in[6];
    const float* ln1_w    = (const float*)d_in[7];
    const float* ln1_b    = (const float*)d_in[8];
    const float* ln2_w    = (const float*)d_in[9];
    const float* ln2_b    = (const float*)d_in[10];
    const float* att_tmk  = (const float*)d_in[11];
    const float* att_tmv  = (const float*)d_in[12];
    const float* att_tmr  = (const float*)d_in[13];
    const float* ffn_tmk  = (const float*)d_in[14];
    const float* ffn_tmr  = (const float*)d_in[15];
    const float* att_tf   = (const float*)d_in[16];
    const float* att_kw   = (const float*)d_in[18];
    const float* att_vw   = (const float*)d_in[19];
    const float* att_rw   = (const float*)d_in[20];
    const float* att_ow   = (const float*)d_in[21];
    const float* ffn_rw   = (const float*)d_in[22];
    const float* ffn_kw   = (const float*)d_in[23];
    const float* ffn_vw   = (const float*)d_in[24];
    const float* spa_dw_w = (const float*)d_in[25];
    const float* spa_dw_b = (const float*)d_in[26];
    const float* spa_pw_w = (const float*)d_in[27];
    const float* spa_pw_b = (const float*)d_in[28];
    const float* state0   = (const float*)d_in[29];
    float* out = (float*)d_out;

    const size_t NF = (size_t)NTOK * F_DIMC;
    char* wsp = (char*)d_ws;
    size_t off = 0;
    auto alloc = [&](size_t bytes) -> void* {
        void* p = wsp + off;
        off += (bytes + 255) & ~(size_t)255;
        return p;
    };
    float* d_buf = (float*)alloc(NF * 4);
    bf16*  xk    = (bf16*)alloc(NF * 2);
    bf16*  xv    = (bf16*)alloc(NF * 2);
    bf16*  xr    = (bf16*)alloc(NF * 2);
    bf16*  ab    = (bf16*)alloc(NF * 2);               // rwkv / dwconv-out (reused)
    bf16*  kkb   = (bf16*)alloc((size_t)NTOK * FHC * 2);
    const size_t WSQ = (size_t)NLAY * F_DIMC * F_DIMC;
    bf16* kwb  = (bf16*)alloc(WSQ * 2);
    bf16* vwb  = (bf16*)alloc(WSQ * 2);
    bf16* rwb  = (bf16*)alloc(WSQ * 2);
    bf16* owb  = (bf16*)alloc(WSQ * 2);
    bf16* frwb = (bf16*)alloc(WSQ * 2);
    bf16* fkwb = (bf16*)alloc((size_t)NLAY * FHC * F_DIMC * 2);
    bf16* fvwb = (bf16*)alloc((size_t)NLAY * F_DIMC * FHC * 2);
    bf16* pwb  = (bf16*)alloc(WSQ * 2);
    float* dwT = (float*)alloc((size_t)NLAY * 49 * F_DIMC * 4);
    if (off > ws_size) return;

    {
        Cvt6 c6;
        c6.s[0] = att_kw;  c6.d[0] = kwb;
        c6.s[1] = att_vw;  c6.d[1] = vwb;
        c6.s[2] = att_rw;  c6.d[2] = rwb;
        c6.s[3] = att_ow;  c6.d[3] = owb;
        c6.s[4] = ffn_rw;  c6.d[4] = frwb;
        c6.s[5] = spa_pw_w; c6.d[5] = pwb;
        cvt6_k<<<dim3(((int)WSQ + 255) / 256, 6), dim3(256), 0, stream>>>(c6, (int)WSQ);
        Cvt2 c2;
        c2.s[0] = ffn_kw; c2.d[0] = fkwb;
        c2.s[1] = ffn_vw; c2.d[1] = fvwb;
        int n2 = NLAY * FHC * F_DIMC;
        cvt2_k<<<dim3((n2 + 255) / 256, 2), dim3(256), 0, stream>>>(c2, n2);
        int n = NLAY * 49 * F_DIMC;
        dw_transpose_k<<<dim3((n + 255) / 256), dim3(256), 0, stream>>>(spa_dw_w, dwT, n);
    }

    stem2_k<<<dim3(IMGH * 10, 4), dim3(256), 0, stream>>>(x, cin_w1, cin_b1, cin_w2, cin_b2, d_buf);

    for (int i = 0; i < NLAY; ++i) {
        const float* sp_ff = state0 + (size_t)(5 * i + 0) * NF;
        const float* sp_at = state0 + (size_t)(5 * i + 1) * NF;
        const float* aa    = state0 + (size_t)(5 * i + 2) * NF;
        const float* bb    = state0 + (size_t)(5 * i + 3) * NF;
        const float* pp    = state0 + (size_t)(5 * i + 4) * NF;
        const float* l1w = ln1_w + i * F_DIMC, *l1b = ln1_b + i * F_DIMC;
        const float* l2w = ln2_w + i * F_DIMC, *l2b = ln2_b + i * F_DIMC;
        const float* tmk = att_tmk + i * F_DIMC, *tmv = att_tmv + i * F_DIMC, *tmr = att_tmr + i * F_DIMC;
        const float* ftmk = ffn_tmk + i * F_DIMC, *ftmr = ffn_tmr + i * F_DIMC;
        const float* tf = att_tf + i * F_DIMC;
        const bf16* kw_i  = kwb  + (size_t)i * F_DIMC * F_DIMC;
        const bf16* vw_i  = vwb  + (size_t)i * F_DIMC * F_DIMC;
        const bf16* rw_i  = rwb  + (size_t)i * F_DIMC * F_DIMC;
        const bf16* ow_i  = owb  + (size_t)i * F_DIMC * F_DIMC;
        const bf16* frw_i = frwb + (size_t)i * F_DIMC * F_DIMC;
        const bf16* fkw_i = fkwb + (size_t)i * FHC * F_DIMC;
        const bf16* fvw_i = fvwb + (size_t)i * F_DIMC * FHC;
        const bf16* pw_i  = pwb  + (size_t)i * F_DIMC * F_DIMC;
        const float* dwT_i = dwT + (size_t)i * 49 * F_DIMC;
        const float* dwb_i = spa_dw_b + i * F_DIMC;
        const float* pwbias_i = spa_pw_b + i * F_DIMC;

        if (i == 0)
            lnmix_sa_k<true><<<dim3(NTOK / 4), dim3(256), 0, stream>>>(
                d_buf, sp_at, ln0_w, ln0_b, l1w, l1b, tmk, tmv, tmr, xk, xv, xr);
        else
            lnmix_sa_k<false><<<dim3(NTOK / 4), dim3(256), 0, stream>>>(
                d_buf, sp_at, ln0_w, ln0_b, l1w, l1b, tmk, tmv, tmr, xk, xv, xr);

        sawkv_k<<<dim3(NTOK / 64, 4), dim3(256), 0, stream>>>(
            xk, xv, xr, kw_i, vw_i, rw_i, aa, bb, pp, tf, ab);

        gemm128_k<3><<<dim3(NTOK / 128, 2), dim3(256), 0, stream>>>(
            ab, ow_i, F_DIMC, F_DIMC, F_DIMC, F_DIMC, d_buf, nullptr, nullptr);

        lnmix_ff_k<<<dim3(NTOK / 4), dim3(256), 0, stream>>>(d_buf, sp_ff, l2w, l2b, ftmk, ftmr, xk, xr);

        gemm128_k<2><<<dim3(NTOK / 128, 8), dim3(256), 0, stream>>>(
            xk, fkw_i, F_DIMC, F_DIMC, F_DIMC, FHC, nullptr, kkb, nullptr);

        fvwrr_k<<<dim3(NTOK / 128, 2), dim3(256), 0, stream>>>(kkb, fvw_i, xr, frw_i, d_buf);

        dwconv2_k<<<dim3(IMGW / 8, IMGH / 8, 4), dim3(64, 4), 0, stream>>>(d_buf, dwT_i, dwb_i, ab);

        gemm128_k<5><<<dim3(NTOK / 128, 2), dim3(256), 0, stream>>>(
            ab, pw_i, F_DIMC, F_DIMC, F_DIMC, F_DIMC, d_buf, nullptr, pwbias_i);
    }

    transpose_out_k<<<dim3(NTOK / 32, F_DIMC / 32), dim3(32, 8), 0, stream>>>(d_buf, out);
}

// Round 5
// 1931.179 us; speedup vs baseline: 1.0107x; 1.0107x over previous
//
#include <hip/hip_runtime.h>
#include <hip/hip_bf16.h>
#include <cstdint>
#include <cstddef>

#define F_DIMC 256
#define FHC    1024
#define IMGH   160
#define IMGW   160
#define NTOK   25600
#define NLAY   4

using bf16 = __hip_bfloat16;
using f16  = _Float16;
typedef __attribute__((ext_vector_type(8))) short bf16x8;
typedef __attribute__((ext_vector_type(4))) float f32x4;

#define MFMA16(a, b, c) __builtin_amdgcn_mfma_f32_16x16x32_bf16((a), (b), (c), 0, 0, 0)

union H4 { f16 h[4]; uint2 u; };
union Pack4 { bf16 h[4]; uint2 u; };

// ---------------- weight converts (merged) ----------------
struct Cvt6 { const float* s[6]; bf16* d[6]; };
__global__ void cvt6_k(Cvt6 a, int n) {
    int z = blockIdx.y;
    int i = blockIdx.x * 256 + threadIdx.x;
    if (i < n) a.d[z][i] = __float2bfloat16(a.s[z][i]);
}
struct Cvt2 { const float* s[2]; bf16* d[2]; };
__global__ void cvt2_k(Cvt2 a, int n) {
    int z = blockIdx.y;
    int i = blockIdx.x * 256 + threadIdx.x;
    if (i < n) a.d[z][i] = __float2bfloat16(a.s[z][i]);
}

// spa_dw_w (L,F,49) -> dwT (L,49,F) fp32
__global__ void dw_transpose_k(const float* __restrict__ src, float* __restrict__ dst, int n) {
    int i = blockIdx.x * 256 + threadIdx.x;
    if (i < n) {
        int f = i & (F_DIMC - 1);
        int lt = i >> 8;
        int t = lt % 49;
        int l = lt / 49;
        dst[i] = src[((size_t)l * F_DIMC + f) * 49 + t];
    }
}

// ---------------- stem: branchless, strip-parallel ---------------------------
__global__ __launch_bounds__(256)
void stem2_k(const float* __restrict__ x, const float* __restrict__ w1,
             const float* __restrict__ b1, const float* __restrict__ w2,
             const float* __restrict__ b2, f16* __restrict__ d)
{
    __shared__ float wts[49][64];
    __shared__ float w1s[64], b1s[64], b2s[64];
    __shared__ float2 xp[7][22];
    const int tid = threadIdx.x;
    const int f0 = blockIdx.y * 64;
    const int y = blockIdx.x / 10;
    const int x0 = (blockIdx.x % 10) * 16;

    for (int idx = tid; idx < 49 * 64; idx += 256) {
        int t = idx >> 6, fl = idx & 63;
        wts[t][fl] = w2[(f0 + fl) * 49 + t];
    }
    if (tid < 64) {
        w1s[tid] = w1[f0 + tid];
        b1s[tid] = b1[f0 + tid];
        b2s[tid] = b2[f0 + tid];
    }
    for (int p = tid; p < 7 * 22; p += 256) {
        int py = p / 22, px = p % 22;
        int gy = y + py - 3, gx = x0 + px - 3;
        bool ok = (unsigned)gy < IMGH && (unsigned)gx < IMGW;
        xp[py][px] = ok ? make_float2(x[gy * IMGW + gx], 1.f) : make_float2(0.f, 0.f);
    }
    __syncthreads();

    const int fl = tid & 63;
    const int xbase = (tid >> 6) * 4;
    float acc[4] = {0.f, 0.f, 0.f, 0.f}, accw[4] = {0.f, 0.f, 0.f, 0.f};
    #pragma unroll
    for (int ky = 0; ky < 7; ++ky) {
        float2 row[10];
        #pragma unroll
        for (int q = 0; q < 10; ++q) row[q] = xp[ky][xbase + q];
        #pragma unroll
        for (int kx = 0; kx < 7; ++kx) {
            float w = wts[ky * 7 + kx][fl];
            #pragma unroll
            for (int j = 0; j < 4; ++j) {
                acc[j]  = fmaf(row[j + kx].x, w, acc[j]);
                accw[j] = fmaf(row[j + kx].y, w, accw[j]);
            }
        }
    }
    const float w1f = w1s[fl], b1f = b1s[fl], b2f = b2s[fl];
    #pragma unroll
    for (int j = 0; j < 4; ++j) {
        float u = fmaf(w1f, acc[j], fmaf(b1f, accw[j], b2f));
        int pix = y * IMGW + x0 + xbase + j;
        d[(size_t)pix * F_DIMC + f0 + fl] = (f16)(u / (1.f + __expf(-4.f * u)));
    }
}

// ---------------- wave-level LayerNorm over F=256 ----------------------------
__device__ __forceinline__ void wave_ln(float* x, const float* __restrict__ w,
                                        const float* __restrict__ b, int lane)
{
    float s = x[0] + x[1] + x[2] + x[3];
    #pragma unroll
    for (int m = 1; m < 64; m <<= 1) s += __shfl_xor(s, m, 64);
    float mu = s * 0.00390625f;
    float t0 = x[0] - mu, t1 = x[1] - mu, t2 = x[2] - mu, t3 = x[3] - mu;
    float v = t0 * t0 + t1 * t1 + t2 * t2 + t3 * t3;
    #pragma unroll
    for (int m = 1; m < 64; m <<= 1) v += __shfl_xor(v, m, 64);
    float inv = rsqrtf(v * 0.00390625f + 1e-5f);
    f32x4 wv = *(const f32x4*)(w + lane * 4);
    f32x4 bv = *(const f32x4*)(b + lane * 4);
    x[0] = t0 * inv * wv[0] + bv[0];
    x[1] = t1 * inv * wv[1] + bv[1];
    x[2] = t2 * inv * wv[2] + bv[2];
    x[3] = t3 * inv * wv[3] + bv[3];
}

template<bool LN0>
__global__ __launch_bounds__(256)
void lnmix_sa_k(f16* __restrict__ d, const float* __restrict__ sp,
                const float* __restrict__ ln0w, const float* __restrict__ ln0b,
                const float* __restrict__ lnw, const float* __restrict__ lnb,
                const float* __restrict__ tmk, const float* __restrict__ tmv,
                const float* __restrict__ tmr,
                bf16* __restrict__ xk, bf16* __restrict__ xv, bf16* __restrict__ xr)
{
    const int lane = threadIdx.x & 63;
    const int n = blockIdx.x * 4 + (threadIdx.x >> 6);
    const int base = n * F_DIMC + lane * 4;
    H4 hv; hv.u = *(const uint2*)(d + base);
    float xo[4] = {(float)hv.h[0], (float)hv.h[1], (float)hv.h[2], (float)hv.h[3]};
    if (LN0) {
        wave_ln(xo, ln0w, ln0b, lane);
        H4 o;
        #pragma unroll
        for (int j = 0; j < 4; ++j) o.h[j] = (f16)xo[j];
        *(uint2*)(d + base) = o.u;
    }
    float xs[4] = {xo[0], xo[1], xo[2], xo[3]};
    wave_ln(xs, lnw, lnb, lane);
    f32x4 spv = *(const f32x4*)(sp + base);
    f32x4 k4 = *(const f32x4*)(tmk + lane * 4);
    f32x4 v4 = *(const f32x4*)(tmv + lane * 4);
    f32x4 r4 = *(const f32x4*)(tmr + lane * 4);
    Pack4 pk, pv, pr;
    #pragma unroll
    for (int j = 0; j < 4; ++j) {
        pk.h[j] = __float2bfloat16(xs[j] * k4[j] + spv[j] * (1.f - k4[j]));
        pv.h[j] = __float2bfloat16(xs[j] * v4[j] + spv[j] * (1.f - v4[j]));
        pr.h[j] = __float2bfloat16(xs[j] * r4[j] + spv[j] * (1.f - r4[j]));
    }
    *(uint2*)(xk + base) = pk.u;
    *(uint2*)(xv + base) = pv.u;
    *(uint2*)(xr + base) = pr.u;
}

__global__ __launch_bounds__(256)
void lnmix_ff_k(const f16* __restrict__ d, const float* __restrict__ sp,
                const float* __restrict__ lnw, const float* __restrict__ lnb,
                const float* __restrict__ tmk, const float* __restrict__ tmr,
                bf16* __restrict__ xk, bf16* __restrict__ xr)
{
    const int lane = threadIdx.x & 63;
    const int n = blockIdx.x * 4 + (threadIdx.x >> 6);
    const int base = n * F_DIMC + lane * 4;
    H4 hv; hv.u = *(const uint2*)(d + base);
    float xs[4] = {(float)hv.h[0], (float)hv.h[1], (float)hv.h[2], (float)hv.h[3]};
    wave_ln(xs, lnw, lnb, lane);
    f32x4 spv = *(const f32x4*)(sp + base);
    f32x4 k4 = *(const f32x4*)(tmk + lane * 4);
    f32x4 r4 = *(const f32x4*)(tmr + lane * 4);
    Pack4 pk, pr;
    #pragma unroll
    for (int j = 0; j < 4; ++j) {
        pk.h[j] = __float2bfloat16(xs[j] * k4[j] + spv[j] * (1.f - k4[j]));
        pr.h[j] = __float2bfloat16(xs[j] * r4[j] + spv[j] * (1.f - r4[j]));
    }
    *(uint2*)(xk + base) = pk.u;
    *(uint2*)(xr + base) = pr.u;
}

// ---------------- WKV single step (f16 G inputs) -> bf16 ---------------------
__global__ __launch_bounds__(256)
void wkv_k(const f16* __restrict__ r_, const f16* __restrict__ k_,
           const f16* __restrict__ v_, const float* __restrict__ aa,
           const float* __restrict__ bb, const float* __restrict__ pp,
           const float* __restrict__ tf, bf16* __restrict__ out)
{
    int i = blockIdx.x * 256 + threadIdx.x;
    int f0 = (i << 2) & (F_DIMC - 1);
    H4 r4; r4.u = *(const uint2*)(r_ + (size_t)i * 4);
    H4 k4; k4.u = *(const uint2*)(k_ + (size_t)i * 4);
    H4 v4; v4.u = *(const uint2*)(v_ + (size_t)i * 4);
    f32x4 a4 = *(const f32x4*)(aa + (size_t)i * 4);
    f32x4 b4 = *(const f32x4*)(bb + (size_t)i * 4);
    f32x4 p4 = *(const f32x4*)(pp + (size_t)i * 4);
    f32x4 t4 = *(const f32x4*)(tf + f0);
    Pack4 po;
    #pragma unroll
    for (int j = 0; j < 4; ++j) {
        float ww = t4[j] + (float)k4.h[j];
        float p = fmaxf(p4[j], ww);
        float e1 = __expf(p4[j] - p);
        float e2 = __expf(ww - p);
        float wkv = (e1 * a4[j] + e2 * (float)v4.h[j]) / (e1 * b4[j] + e2);
        po.h[j] = __float2bfloat16((float)r4.h[j] * wkv);
    }
    *(uint2*)(out + (size_t)i * 4) = po.u;
}

// ---------------- swizzled staging + fragment loads --------------------------
// 128-col rows (256B), 128 rows => 2048 chunks; lda in elems
__device__ __forceinline__ void stage_swz16(const bf16* __restrict__ g, int lda,
                                            bf16* lds, int tid)
{
    #pragma unroll
    for (int s = 0; s < 8; ++s) {
        int chunk = s * 256 + tid;
        int row = chunk >> 4, c16 = chunk & 15;
        int gc = c16 ^ (row & 15);
        __builtin_amdgcn_global_load_lds(
            (const __attribute__((address_space(1))) void*)(g + (size_t)row * lda + gc * 8),
            (__attribute__((address_space(3))) void*)(lds + chunk * 8), 16, 0, 0);
    }
}

template<int RB>
__device__ __forceinline__ bf16x8 frag_ld(const bf16* lds, int row, int cb)
{
    return *(const bf16x8*)((const char*)lds + row * RB + (cb ^ ((row & 15) << 4)));
}

// ---------------- SA GEMM: z-batched 128x128 tiles, K=256, f16 out -----------
struct G3 { const bf16* A[3]; const bf16* W[3]; f16* C[3]; };
__global__ __launch_bounds__(256, 2)
void gemm3_k(G3 g)
{
    __shared__ __align__(16) bf16 As[128 * 128];
    __shared__ __align__(16) bf16 Bs[128 * 128];
    const int z = blockIdx.z;
    const bf16* __restrict__ A  = g.A[z];
    const bf16* __restrict__ Bw = g.W[z];
    f16* __restrict__ C         = g.C[z];
    const int tid = threadIdx.x, lane = tid & 63, wave = tid >> 6;
    const int wr = wave >> 1, wc = wave & 1;
    const int lr = lane & 15, hi = lane >> 4;
    const int m0 = blockIdx.x * 128, n0 = blockIdx.y * 128;

    f32x4 acc[4][4];
    #pragma unroll
    for (int m = 0; m < 4; ++m)
        #pragma unroll
        for (int n = 0; n < 4; ++n) acc[m][n] = (f32x4){0.f, 0.f, 0.f, 0.f};

    #pragma unroll
    for (int kt = 0; kt < 256; kt += 128) {
        stage_swz16(A + (size_t)m0 * 256 + kt, 256, As, tid);
        stage_swz16(Bw + (size_t)n0 * 256 + kt, 256, Bs, tid);
        __syncthreads();
        #pragma unroll
        for (int ks = 0; ks < 4; ++ks) {
            int cb = ks * 64 + hi * 16;
            bf16x8 a[4], b[4];
            #pragma unroll
            for (int mf = 0; mf < 4; ++mf) a[mf] = frag_ld<256>(As, wr * 64 + mf * 16 + lr, cb);
            #pragma unroll
            for (int nf = 0; nf < 4; ++nf) b[nf] = frag_ld<256>(Bs, wc * 64 + nf * 16 + lr, cb);
            #pragma unroll
            for (int mf = 0; mf < 4; ++mf)
                #pragma unroll
                for (int nf = 0; nf < 4; ++nf)
                    acc[mf][nf] = MFMA16(a[mf], b[nf], acc[mf][nf]);
        }
        __syncthreads();
    }

    const int lr0 = hi * 4;
    #pragma unroll
    for (int mf = 0; mf < 4; ++mf)
        #pragma unroll
        for (int nf = 0; nf < 4; ++nf) {
            int col = n0 + wc * 64 + nf * 16 + lr;
            #pragma unroll
            for (int j = 0; j < 4; ++j) {
                int row = m0 + wr * 64 + mf * 16 + lr0 + j;
                float v = acc[mf][nf][j];
                if (z == 2) v = 1.f / (1.f + __expf(-v));
                C[(size_t)row * F_DIMC + col] = (f16)v;
            }
        }
}

// ---------------- gemm128: 128x128 tile, compile-time K, fused epilogues -----
// EPI: 2 = relu^2 -> bf16, 3 = Cf16 += v, 5 = Cf16 += v + bias[col]
template<int EPI, int K>
__global__ __launch_bounds__(256, 2)
void gemm128_k(const bf16* __restrict__ A, const bf16* __restrict__ Bw,
               int Nout, f16* __restrict__ Cf, bf16* __restrict__ Cb,
               const float* __restrict__ bias)
{
    __shared__ __align__(16) bf16 As[128 * 128];
    __shared__ __align__(16) bf16 Bs[128 * 128];
    const int tid = threadIdx.x, lane = tid & 63, wave = tid >> 6;
    const int wr = wave >> 1, wc = wave & 1;
    const int lr = lane & 15, hi = lane >> 4;
    const int m0 = blockIdx.x * 128, n0 = blockIdx.y * 128;

    f32x4 acc[4][4];
    #pragma unroll
    for (int m = 0; m < 4; ++m)
        #pragma unroll
        for (int n = 0; n < 4; ++n) acc[m][n] = (f32x4){0.f, 0.f, 0.f, 0.f};

    #pragma unroll
    for (int kt = 0; kt < K; kt += 128) {
        stage_swz16(A + (size_t)m0 * K + kt, K, As, tid);
        stage_swz16(Bw + (size_t)n0 * K + kt, K, Bs, tid);
        __syncthreads();
        #pragma unroll
        for (int ks = 0; ks < 4; ++ks) {
            int cb = ks * 64 + hi * 16;
            bf16x8 a[4], b[4];
            #pragma unroll
            for (int mf = 0; mf < 4; ++mf) a[mf] = frag_ld<256>(As, wr * 64 + mf * 16 + lr, cb);
            #pragma unroll
            for (int nf = 0; nf < 4; ++nf) b[nf] = frag_ld<256>(Bs, wc * 64 + nf * 16 + lr, cb);
            #pragma unroll
            for (int mf = 0; mf < 4; ++mf)
                #pragma unroll
                for (int nf = 0; nf < 4; ++nf)
                    acc[mf][nf] = MFMA16(a[mf], b[nf], acc[mf][nf]);
        }
        __syncthreads();
    }

    const int lr0 = hi * 4;
    #pragma unroll
    for (int mf = 0; mf < 4; ++mf)
        #pragma unroll
        for (int nf = 0; nf < 4; ++nf) {
            int col = n0 + wc * 64 + nf * 16 + lr;
            #pragma unroll
            for (int j = 0; j < 4; ++j) {
                int row = m0 + wr * 64 + mf * 16 + lr0 + j;
                size_t cidx = (size_t)row * Nout + col;
                float v = acc[mf][nf][j];
                if constexpr (EPI == 2) { float t = fmaxf(v, 0.f); Cb[cidx] = __float2bfloat16(t * t); }
                else if constexpr (EPI == 3) Cf[cidx] = (f16)((float)Cf[cidx] + v);
                else if constexpr (EPI == 5) Cf[cidx] = (f16)((float)Cf[cidx] + v + bias[col]);
            }
        }
}

// ---------------- fvw GEMM (K=1024) with fused rr = sigmoid(xr@rw^T) ---------
__global__ __launch_bounds__(256, 2)
void fvwrr_k(const bf16* __restrict__ kkb, const bf16* __restrict__ fvw,
             const bf16* __restrict__ xr, const bf16* __restrict__ rw,
             f16* __restrict__ d)
{
    __shared__ __align__(16) bf16 As[128 * 128];
    __shared__ __align__(16) bf16 Bs[128 * 128];
    const int tid = threadIdx.x, lane = tid & 63, wave = tid >> 6;
    const int wr = wave >> 1, wc = wave & 1;
    const int lr = lane & 15, hi = lane >> 4;
    const int m0 = blockIdx.x * 128, n0 = blockIdx.y * 128;

    f32x4 arr[4][4], am[4][4];
    #pragma unroll
    for (int m = 0; m < 4; ++m)
        #pragma unroll
        for (int n = 0; n < 4; ++n) {
            arr[m][n] = (f32x4){0.f, 0.f, 0.f, 0.f};
            am[m][n]  = (f32x4){0.f, 0.f, 0.f, 0.f};
        }

    #pragma unroll
    for (int kt = 0; kt < 256; kt += 128) {
        stage_swz16(xr + (size_t)m0 * 256 + kt, 256, As, tid);
        stage_swz16(rw + (size_t)n0 * 256 + kt, 256, Bs, tid);
        __syncthreads();
        #pragma unroll
        for (int ks = 0; ks < 4; ++ks) {
            int cb = ks * 64 + hi * 16;
            bf16x8 a[4], b[4];
            #pragma unroll
            for (int mf = 0; mf < 4; ++mf) a[mf] = frag_ld<256>(As, wr * 64 + mf * 16 + lr, cb);
            #pragma unroll
            for (int nf = 0; nf < 4; ++nf) b[nf] = frag_ld<256>(Bs, wc * 64 + nf * 16 + lr, cb);
            #pragma unroll
            for (int mf = 0; mf < 4; ++mf)
                #pragma unroll
                for (int nf = 0; nf < 4; ++nf)
                    arr[mf][nf] = MFMA16(a[mf], b[nf], arr[mf][nf]);
        }
        __syncthreads();
    }
    #pragma unroll
    for (int kt = 0; kt < 1024; kt += 128) {
        stage_swz16(kkb + (size_t)m0 * 1024 + kt, 1024, As, tid);
        stage_swz16(fvw + (size_t)n0 * 1024 + kt, 1024, Bs, tid);
        __syncthreads();
        #pragma unroll
        for (int ks = 0; ks < 4; ++ks) {
            int cb = ks * 64 + hi * 16;
            bf16x8 a[4], b[4];
            #pragma unroll
            for (int mf = 0; mf < 4; ++mf) a[mf] = frag_ld<256>(As, wr * 64 + mf * 16 + lr, cb);
            #pragma unroll
            for (int nf = 0; nf < 4; ++nf) b[nf] = frag_ld<256>(Bs, wc * 64 + nf * 16 + lr, cb);
            #pragma unroll
            for (int mf = 0; mf < 4; ++mf)
                #pragma unroll
                for (int nf = 0; nf < 4; ++nf)
                    am[mf][nf] = MFMA16(a[mf], b[nf], am[mf][nf]);
        }
        __syncthreads();
    }

    const int lr0 = hi * 4;
    #pragma unroll
    for (int mf = 0; mf < 4; ++mf)
        #pragma unroll
        for (int nf = 0; nf < 4; ++nf) {
            int col = n0 + wc * 64 + nf * 16 + lr;
            #pragma unroll
            for (int j = 0; j < 4; ++j) {
                int row = m0 + wr * 64 + mf * 16 + lr0 + j;
                size_t cidx = (size_t)row * F_DIMC + col;
                float rr = 1.f / (1.f + __expf(-arr[mf][nf][j]));
                d[cidx] = (f16)((float)d[cidx] + rr * am[mf][nf][j]);
            }
        }
}

// ---------------- depthwise 7x7 conv: 8x8 tile, register row reuse -----------
__global__ __launch_bounds__(256)
void dwconv2_k(const f16* __restrict__ d, const float* __restrict__ wT,
               const float* __restrict__ bias, bf16* __restrict__ out)
{
    __shared__ float patch[196][64];
    __shared__ float wt[49][64];
    const int lane = threadIdx.x;
    const int ty = threadIdx.y;
    const int f0 = blockIdx.z * 64;
    const int w0 = blockIdx.x * 8, h0 = blockIdx.y * 8;

    for (int t = ty; t < 49; t += 4) wt[t][lane] = wT[t * F_DIMC + f0 + lane];
    for (int p = ty; p < 196; p += 4) {
        int py = p / 14, px = p % 14;
        int gy = h0 + py - 3, gx = w0 + px - 3;
        float v = 0.f;
        if ((unsigned)gy < IMGH && (unsigned)gx < IMGW)
            v = (float)d[(size_t)(gy * IMGW + gx) * F_DIMC + f0 + lane];
        patch[p][lane] = v;
    }
    __syncthreads();

    const float b = bias[f0 + lane];
    #pragma unroll
    for (int rr = 0; rr < 2; ++rr) {
        int ry = ty * 2 + rr;
        float acc8[8];
        #pragma unroll
        for (int px = 0; px < 8; ++px) acc8[px] = b;
        #pragma unroll
        for (int ky = 0; ky < 7; ++ky) {
            float rowv[14];
            #pragma unroll
            for (int c = 0; c < 14; ++c) rowv[c] = patch[(ry + ky) * 14 + c][lane];
            #pragma unroll
            for (int kx = 0; kx < 7; ++kx) {
                float w = wt[ky * 7 + kx][lane];
                #pragma unroll
                for (int px = 0; px < 8; ++px)
                    acc8[px] = fmaf(rowv[px + kx], w, acc8[px]);
            }
        }
        #pragma unroll
        for (int px = 0; px < 8; ++px)
            out[(size_t)((h0 + ry) * IMGW + (w0 + px)) * F_DIMC + f0 + lane] = __float2bfloat16(acc8[px]);
    }
}

// ---------------- final (N,F) f16 -> (F,H,W) f32 transpose -------------------
__global__ __launch_bounds__(256)
void transpose_out_k(const f16* __restrict__ d, float* __restrict__ out)
{
    __shared__ float tile[32][33];
    const int n0 = blockIdx.x * 32, f0 = blockIdx.y * 32;
    const int tx = threadIdx.x, ty = threadIdx.y;
    for (int r = ty; r < 32; r += 8) tile[r][tx] = (float)d[(size_t)(n0 + r) * F_DIMC + f0 + tx];
    __syncthreads();
    for (int r = ty; r < 32; r += 8) out[(size_t)(f0 + r) * NTOK + n0 + tx] = tile[tx][r];
}

// =============================================================================
extern "C" void kernel_launch(void* const* d_in, const int* in_sizes, int n_in,
                              void* d_out, int out_size, void* d_ws, size_t ws_size,
                              hipStream_t stream)
{
    if (n_in < 30) return;
    const float* x        = (const float*)d_in[0];
    const float* cin_w1   = (const float*)d_in[1];
    const float* cin_b1   = (const float*)d_in[2];
    const float* cin_w2   = (const float*)d_in[3];
    const float* cin_b2   = (const float*)d_in[4];
    const float* ln0_w    = (const float*)d_in[5];
    const float* ln0_b    = (const float*)d_in[6];
    const float* ln1_w    = (const float*)d_in[7];
    const float* ln1_b    = (const float*)d_in[8];
    const float* ln2_w    = (const float*)d_in[9];
    const float* ln2_b    = (const float*)d_in[10];
    const float* att_tmk  = (const float*)d_in[11];
    const float* att_tmv  = (const float*)d_in[12];
    const float* att_tmr  = (const float*)d_in[13];
    const float* ffn_tmk  = (const float*)d_in[14];
    const float* ffn_tmr  = (const float*)d_in[15];
    const float* att_tf   = (const float*)d_in[16];
    const float* att_kw   = (const float*)d_in[18];
    const float* att_vw   = (const float*)d_in[19];
    const float* att_rw   = (const float*)d_in[20];
    const float* att_ow   = (const float*)d_in[21];
    const float* ffn_rw   = (const float*)d_in[22];
    const float* ffn_kw   = (const float*)d_in[23];
    const float* ffn_vw   = (const float*)d_in[24];
    const float* spa_dw_w = (const float*)d_in[25];
    const float* spa_dw_b = (const float*)d_in[26];
    const float* spa_pw_w = (const float*)d_in[27];
    const float* spa_pw_b = (const float*)d_in[28];
    const float* state0   = (const float*)d_in[29];
    float* out = (float*)d_out;

    const size_t NF = (size_t)NTOK * F_DIMC;
    char* wsp = (char*)d_ws;
    size_t off = 0;
    auto alloc = [&](size_t bytes) -> void* {
        void* p = wsp + off;
        off += (bytes + 255) & ~(size_t)255;
        return p;
    };
    f16*   d_buf = (f16*)alloc(NF * 2);
    f16*   Gk    = (f16*)alloc(NF * 2);
    f16*   Gv    = (f16*)alloc(NF * 2);
    f16*   Gr    = (f16*)alloc(NF * 2);
    bf16*  xk    = (bf16*)alloc(NF * 2);
    bf16*  xv    = (bf16*)alloc(NF * 2);
    bf16*  xr    = (bf16*)alloc(NF * 2);
    bf16*  ab    = (bf16*)alloc(NF * 2);
    bf16*  kkb   = (bf16*)alloc((size_t)NTOK * FHC * 2);
    const size_t WSQ = (size_t)NLAY * F_DIMC * F_DIMC;
    bf16* kwb  = (bf16*)alloc(WSQ * 2);
    bf16* vwb  = (bf16*)alloc(WSQ * 2);
    bf16* rwb  = (bf16*)alloc(WSQ * 2);
    bf16* owb  = (bf16*)alloc(WSQ * 2);
    bf16* frwb = (bf16*)alloc(WSQ * 2);
    bf16* fkwb = (bf16*)alloc((size_t)NLAY * FHC * F_DIMC * 2);
    bf16* fvwb = (bf16*)alloc((size_t)NLAY * F_DIMC * FHC * 2);
    bf16* pwb  = (bf16*)alloc(WSQ * 2);
    float* dwT = (float*)alloc((size_t)NLAY * 49 * F_DIMC * 4);
    if (off > ws_size) return;

    {
        Cvt6 c6;
        c6.s[0] = att_kw;  c6.d[0] = kwb;
        c6.s[1] = att_vw;  c6.d[1] = vwb;
        c6.s[2] = att_rw;  c6.d[2] = rwb;
        c6.s[3] = att_ow;  c6.d[3] = owb;
        c6.s[4] = ffn_rw;  c6.d[4] = frwb;
        c6.s[5] = spa_pw_w; c6.d[5] = pwb;
        cvt6_k<<<dim3(((int)WSQ + 255) / 256, 6), dim3(256), 0, stream>>>(c6, (int)WSQ);
        Cvt2 c2;
        c2.s[0] = ffn_kw; c2.d[0] = fkwb;
        c2.s[1] = ffn_vw; c2.d[1] = fvwb;
        int n2 = NLAY * FHC * F_DIMC;
        cvt2_k<<<dim3((n2 + 255) / 256, 2), dim3(256), 0, stream>>>(c2, n2);
        int n = NLAY * 49 * F_DIMC;
        dw_transpose_k<<<dim3((n + 255) / 256), dim3(256), 0, stream>>>(spa_dw_w, dwT, n);
    }

    stem2_k<<<dim3(IMGH * 10, 4), dim3(256), 0, stream>>>(x, cin_w1, cin_b1, cin_w2, cin_b2, d_buf);

    for (int i = 0; i < NLAY; ++i) {
        const float* sp_ff = state0 + (size_t)(5 * i + 0) * NF;
        const float* sp_at = state0 + (size_t)(5 * i + 1) * NF;
        const float* aa    = state0 + (size_t)(5 * i + 2) * NF;
        const float* bb    = state0 + (size_t)(5 * i + 3) * NF;
        const float* pp    = state0 + (size_t)(5 * i + 4) * NF;
        const float* l1w = ln1_w + i * F_DIMC, *l1b = ln1_b + i * F_DIMC;
        const float* l2w = ln2_w + i * F_DIMC, *l2b = ln2_b + i * F_DIMC;
        const float* tmk = att_tmk + i * F_DIMC, *tmv = att_tmv + i * F_DIMC, *tmr = att_tmr + i * F_DIMC;
        const float* ftmk = ffn_tmk + i * F_DIMC, *ftmr = ffn_tmr + i * F_DIMC;
        const float* tf = att_tf + i * F_DIMC;
        const bf16* kw_i  = kwb  + (size_t)i * F_DIMC * F_DIMC;
        const bf16* vw_i  = vwb  + (size_t)i * F_DIMC * F_DIMC;
        const bf16* rw_i  = rwb  + (size_t)i * F_DIMC * F_DIMC;
        const bf16* ow_i  = owb  + (size_t)i * F_DIMC * F_DIMC;
        const bf16* frw_i = frwb + (size_t)i * F_DIMC * F_DIMC;
        const bf16* fkw_i = fkwb + (size_t)i * FHC * F_DIMC;
        const bf16* fvw_i = fvwb + (size_t)i * F_DIMC * FHC;
        const bf16* pw_i  = pwb  + (size_t)i * F_DIMC * F_DIMC;
        const float* dwT_i = dwT + (size_t)i * 49 * F_DIMC;
        const float* dwb_i = spa_dw_b + i * F_DIMC;
        const float* pwbias_i = spa_pw_b + i * F_DIMC;

        if (i == 0)
            lnmix_sa_k<true><<<dim3(NTOK / 4), dim3(256), 0, stream>>>(
                d_buf, sp_at, ln0_w, ln0_b, l1w, l1b, tmk, tmv, tmr, xk, xv, xr);
        else
            lnmix_sa_k<false><<<dim3(NTOK / 4), dim3(256), 0, stream>>>(
                d_buf, sp_at, ln0_w, ln0_b, l1w, l1b, tmk, tmv, tmr, xk, xv, xr);

        G3 g3;
        g3.A[0] = xk; g3.A[1] = xv; g3.A[2] = xr;
        g3.W[0] = kw_i; g3.W[1] = vw_i; g3.W[2] = rw_i;
        g3.C[0] = Gk; g3.C[1] = Gv; g3.C[2] = Gr;
        gemm3_k<<<dim3(NTOK / 128, 2, 3), dim3(256), 0, stream>>>(g3);

        wkv_k<<<dim3((int)(NF / 4 / 256)), dim3(256), 0, stream>>>(Gr, Gk, Gv, aa, bb, pp, tf, ab);

        gemm128_k<3, 256><<<dim3(NTOK / 128, 2), dim3(256), 0, stream>>>(
            ab, ow_i, F_DIMC, d_buf, nullptr, nullptr);

        lnmix_ff_k<<<dim3(NTOK / 4), dim3(256), 0, stream>>>(d_buf, sp_ff, l2w, l2b, ftmk, ftmr, xk, xr);

        gemm128_k<2, 256><<<dim3(NTOK / 128, 8), dim3(256), 0, stream>>>(
            xk, fkw_i, FHC, nullptr, kkb, nullptr);

        fvwrr_k<<<dim3(NTOK / 128, 2), dim3(256), 0, stream>>>(kkb, fvw_i, xr, frw_i, d_buf);

        dwconv2_k<<<dim3(IMGW / 8, IMGH / 8, 4), dim3(64, 4), 0, stream>>>(d_buf, dwT_i, dwb_i, ab);

        gemm128_k<5, 256><<<dim3(NTOK / 128, 2), dim3(256), 0, stream>>>(
            ab, pw_i, F_DIMC, d_buf, nullptr, pwbias_i);
    }

    transpose_out_k<<<dim3(NTOK / 32, F_DIMC / 32), dim3(32, 8), 0, stream>>>(d_buf, out);
}